// Round 3
// baseline (393.017 us; speedup 1.0000x reference)
//
#include <hip/hip_runtime.h>
#include <hip/hip_bf16.h>

#define BATCH   4096
#define DIM     64
#define HID     256
#define TSTEPS  200
#define SROWS   16                 // samples per block (MFMA N)
#define NBLOCKS (BATCH / SROWS)    // 256 blocks = 1 per CU
#define NTH     512                // 8 waves, 2 per SIMD

#define HP  264   // shorts: h1s/h2s row stride ([sample][h])
#define YPB 72    // shorts: ybt row stride ([sample][d])

typedef __bf16 bf16_t;
typedef bf16_t bf16x8 __attribute__((ext_vector_type(8)));
typedef float  f32x4  __attribute__((ext_vector_type(4)));

__device__ __forceinline__ unsigned short f2bf(float f) {
    unsigned u = __builtin_bit_cast(unsigned, f);
    u += 0x7FFFu + ((u >> 16) & 1u);   // RNE
    return (unsigned short)(u >> 16);
}

#if __has_builtin(__builtin_amdgcn_cvt_pk_bf16_f32)
__device__ __forceinline__ unsigned pk2(float lo, float hi) {
    return __builtin_bit_cast(unsigned, __builtin_amdgcn_cvt_pk_bf16_f32(lo, hi));
}
#else
__device__ __forceinline__ unsigned pk2(float lo, float hi) {
    return (unsigned)f2bf(lo) | ((unsigned)f2bf(hi) << 16);
}
#endif

// LDS-only barrier: drain LDS ops (lgkmcnt) but NOT the global output
// stores (vmcnt) -- __syncthreads() would drain vmcnt(0) and put the
// per-step output stores on the critical path every iteration.
__device__ __forceinline__ void bar_lds() {
    asm volatile("s_waitcnt lgkmcnt(0)" ::: "memory");
    __builtin_amdgcn_s_barrier();
    asm volatile("" ::: "memory");
}

// ---------------------------------------------------------------------------
// Weight prep: fp32 row-major W[K][M] -> bf16 MFMA A-fragment order of W^T.
//
// The hidden dim (H=256) uses a sigma-PERMUTED storage order so the GEMM1/2
// epilogues can write one contiguous b128 per lane:
//   stored position p = w*32 + quad*8 + mt*4 + r  <->  logical h-index
//   pi(p)            = w*32 + mt*16  + quad*4 + r
// The MFMA m-side maps through as identity (A-frag m = g*16+l16 and the C/D
// row mu = quad*4+r both land at logical g*16+mu), so only the K-side of
// W2 and W3 needs the permutation:
//   elem j of an A-frag reads logical k = kk*32 + (j>>2)*16 + quad*4 + (j&3)
// W1's K-dim is the y-dim (unpermuted): k = kk*32 + quad*8 + j.
//   W1^T: u = (mt*2+kk)*64+lane            mt:0..15, kk:0..1
//   W2^T: u = 2048 + (mt*8+kk)*64+lane     mt:0..15, kk:0..7
//   W3^T: u = 10240 + (mt*8+kk)*64+lane    mt:0..3,  kk:0..7
// ---------------------------------------------------------------------------
__global__ void prep_weights(const float* __restrict__ W1,
                             const float* __restrict__ W2,
                             const float* __restrict__ W3,
                             unsigned short* __restrict__ ws) {
    int u = blockIdx.x * blockDim.x + threadIdx.x;
    if (u >= 12288) return;
    const int lane = u & 63, l16 = lane & 15, quad = lane >> 4;
    const float* src; int ld, m, kk; bool perm;
    if (u < 2048) {
        int r = u >> 6; kk = r & 1; int mt = r >> 1;
        src = W1; ld = 256; m = mt * 16 + l16; perm = false;
    } else if (u < 10240) {
        int r = (u - 2048) >> 6; kk = r & 7; int mt = r >> 3;
        src = W2; ld = 256; m = mt * 16 + l16; perm = true;
    } else {
        int r = (u - 10240) >> 6; kk = r & 7; int mt = r >> 3;
        src = W3; ld = 64;  m = mt * 16 + l16; perm = true;
    }
    unsigned short tmp[8] __attribute__((aligned(16)));
    #pragma unroll
    for (int j = 0; j < 8; ++j) {
        int k = perm ? kk * 32 + ((j >> 2) << 4) + quad * 4 + (j & 3)
                     : kk * 32 + quad * 8 + j;
        tmp[j] = f2bf(src[(size_t)k * ld + m]);
    }
    *(uint4*)(ws + (size_t)u * 8) = *(const uint4*)tmp;
}

// ---------------------------------------------------------------------------
// Persistent ODE kernel, transposed: h^T[H x 16 samples].
// 8 waves / 2 per SIMD. A = weight^T frags (registers/AGPRs), B =
// activations^T (LDS), C/D: row = h-idx (quad*4+r), col = sample (l16).
// Biases pre-loaded into the MFMA C operand. sigma-permuted h-layout ->
// each epilogue is a single ds_write_b128 per lane.
// ---------------------------------------------------------------------------
__global__ void __launch_bounds__(NTH, 2)
ode_kernel(const float* __restrict__ y0,
           const float* __restrict__ tarr,
           const float* __restrict__ b1,
           const float* __restrict__ b2,
           const float* __restrict__ b3,
           const unsigned short* __restrict__ wf,
           float* __restrict__ out) {
    __shared__ __align__(16) unsigned short ybt[SROWS * YPB];
    __shared__ __align__(16) unsigned short h1s[SROWS * HP];
    __shared__ __align__(16) unsigned short h2s[SROWS * HP];

    const int tid  = threadIdx.x;
    const int w    = tid >> 6;        // wave 0..7
    const int lane = tid & 63;
    const int l16  = lane & 15;       // sample within tile
    const int quad = lane >> 4;
    const int b0   = blockIdx.x * SROWS;

    const float dt = tarr[1] - tarr[0];

    // --- resident weight fragments ---
    const bf16x8* wv = (const bf16x8*)wf;
    bf16x8 w1f[2][2], w2f[2][8], w3f[8];
    #pragma unroll
    for (int mt = 0; mt < 2; ++mt) {
        const int g = w * 2 + mt;
        #pragma unroll
        for (int kk = 0; kk < 2; ++kk) w1f[mt][kk] = wv[(g * 2 + kk) * 64 + lane];
        #pragma unroll
        for (int kk = 0; kk < 8; ++kk) w2f[mt][kk] = wv[2048 + (g * 8 + kk) * 64 + lane];
    }
    if (w < 4)
        #pragma unroll
        for (int kk = 0; kk < 8; ++kk) w3f[kk] = wv[10240 + (w * 8 + kk) * 64 + lane];

    // --- biases in MFMA C/D layout (logical row = base + quad*4 + r) ---
    f32x4 binit1[2], binit2[2], binit3;
    #pragma unroll
    for (int mt = 0; mt < 2; ++mt)
        #pragma unroll
        for (int r = 0; r < 4; ++r) {
            binit1[mt][r] = b1[w * 32 + mt * 16 + quad * 4 + r];
            binit2[mt][r] = b2[w * 32 + mt * 16 + quad * 4 + r];
        }

    // --- init y-state (waves 0-3) + t=0 output + ybt ---
    float yreg[4];
    float* outp = out;   // running per-thread output pointer (waves 0-3)
    if (w < 4) {
        #pragma unroll
        for (int r = 0; r < 4; ++r) binit3[r] = b3[w * 16 + quad * 4 + r];
        outp = out + (size_t)(b0 + l16) * (TSTEPS * DIM) + w * 16 + quad * 4;
        float4 v = *(const float4*)&y0[(size_t)(b0 + l16) * DIM + w * 16 + quad * 4];
        yreg[0] = v.x; yreg[1] = v.y; yreg[2] = v.z; yreg[3] = v.w;
        uint2 p; p.x = pk2(v.x, v.y); p.y = pk2(v.z, v.w);
        *(uint2*)&ybt[l16 * YPB + w * 16 + quad * 4] = p;
        *(float4*)outp = v;
        outp += DIM;
    }
    bar_lds();

    const unsigned short* ybase  = &ybt[l16 * YPB];
    const unsigned short* h1base = &h1s[l16 * HP];
    const unsigned short* h2base = &h2s[l16 * HP];
    // sigma-layout epilogue offset: one contiguous 16B slot per lane
    const int ep_off = l16 * HP + w * 32 + quad * 8;

    for (int t = 1; t < TSTEPS; ++t) {
        // ---- GEMM1: h1^T = relu(W1^T @ y^T + b1) ----
        {
            f32x4 acc[2] = {binit1[0], binit1[1]};
            bf16x8 bfr[2];
            #pragma unroll
            for (int kk = 0; kk < 2; ++kk)
                bfr[kk] = *(const bf16x8*)&ybase[kk * 32 + quad * 8];
            #pragma unroll
            for (int kk = 0; kk < 2; ++kk)
                #pragma unroll
                for (int mt = 0; mt < 2; ++mt)
                    acc[mt] = __builtin_amdgcn_mfma_f32_16x16x32_bf16(
                        w1f[mt][kk], bfr[kk], acc[mt], 0, 0, 0);
            uint4 p;
            p.x = pk2(acc[0][0] > 0.f ? acc[0][0] : 0.f, acc[0][1] > 0.f ? acc[0][1] : 0.f);
            p.y = pk2(acc[0][2] > 0.f ? acc[0][2] : 0.f, acc[0][3] > 0.f ? acc[0][3] : 0.f);
            p.z = pk2(acc[1][0] > 0.f ? acc[1][0] : 0.f, acc[1][1] > 0.f ? acc[1][1] : 0.f);
            p.w = pk2(acc[1][2] > 0.f ? acc[1][2] : 0.f, acc[1][3] > 0.f ? acc[1][3] : 0.f);
            *(uint4*)&h1s[ep_off] = p;
        }
        bar_lds();

        // ---- GEMM2: h2^T = relu(W2^T @ h1^T + b2) ----
        {
            f32x4 acc[2] = {binit2[0], binit2[1]};
            bf16x8 bfr[8];
            #pragma unroll
            for (int kk = 0; kk < 8; ++kk)
                bfr[kk] = *(const bf16x8*)&h1base[kk * 32 + quad * 8];
            #pragma unroll
            for (int kk = 0; kk < 8; ++kk)
                #pragma unroll
                for (int mt = 0; mt < 2; ++mt)
                    acc[mt] = __builtin_amdgcn_mfma_f32_16x16x32_bf16(
                        w2f[mt][kk], bfr[kk], acc[mt], 0, 0, 0);
            uint4 p;
            p.x = pk2(acc[0][0] > 0.f ? acc[0][0] : 0.f, acc[0][1] > 0.f ? acc[0][1] : 0.f);
            p.y = pk2(acc[0][2] > 0.f ? acc[0][2] : 0.f, acc[0][3] > 0.f ? acc[0][3] : 0.f);
            p.z = pk2(acc[1][0] > 0.f ? acc[1][0] : 0.f, acc[1][1] > 0.f ? acc[1][1] : 0.f);
            p.w = pk2(acc[1][2] > 0.f ? acc[1][2] : 0.f, acc[1][3] > 0.f ? acc[1][3] : 0.f);
            *(uint4*)&h2s[ep_off] = p;
        }
        bar_lds();

        // ---- GEMM3 (waves 0-3): dy^T = W3^T @ h2^T + b3; y += dt*dy ----
        if (w < 4) {
            f32x4 accA = binit3;
            f32x4 accB = {0.f, 0.f, 0.f, 0.f};   // 2 chains halve dep latency
            bf16x8 bfr[8];
            #pragma unroll
            for (int kk = 0; kk < 8; ++kk)
                bfr[kk] = *(const bf16x8*)&h2base[kk * 32 + quad * 8];
            #pragma unroll
            for (int k = 0; k < 4; ++k) {
                accA = __builtin_amdgcn_mfma_f32_16x16x32_bf16(
                    w3f[k], bfr[k], accA, 0, 0, 0);
                accB = __builtin_amdgcn_mfma_f32_16x16x32_bf16(
                    w3f[k + 4], bfr[k + 4], accB, 0, 0, 0);
            }
            f32x4 acc = accA + accB;
            #pragma unroll
            for (int r = 0; r < 4; ++r)
                yreg[r] = __builtin_fmaf(dt, acc[r], yreg[r]);
            uint2 p; p.x = pk2(yreg[0], yreg[1]); p.y = pk2(yreg[2], yreg[3]);
            *(uint2*)&ybt[l16 * YPB + w * 16 + quad * 4] = p;
            float4 ov; ov.x = yreg[0]; ov.y = yreg[1]; ov.z = yreg[2]; ov.w = yreg[3];
            *(float4*)outp = ov;
            outp += DIM;
        }
        bar_lds();
    }
}

extern "C" void kernel_launch(void* const* d_in, const int* in_sizes, int n_in,
                              void* d_out, int out_size, void* d_ws, size_t ws_size,
                              hipStream_t stream) {
    const float* y0 = (const float*)d_in[0];
    const float* t  = (const float*)d_in[1];
    const float* W1 = (const float*)d_in[2];
    const float* b1 = (const float*)d_in[3];
    const float* W2 = (const float*)d_in[4];
    const float* b2 = (const float*)d_in[5];
    const float* W3 = (const float*)d_in[6];
    const float* b3 = (const float*)d_in[7];
    float* out = (float*)d_out;
    unsigned short* wf = (unsigned short*)d_ws;   // 12288 * 16B = 192 KiB

    prep_weights<<<48, 256, 0, stream>>>(W1, W2, W3, wf);
    ode_kernel<<<NBLOCKS, NTH, 0, stream>>>(y0, t, b1, b2, b3, wf, out);
}

// Round 4
// 383.962 us; speedup vs baseline: 1.0236x; 1.0236x over previous
//
#include <hip/hip_runtime.h>
#include <hip/hip_bf16.h>

#define BATCH   4096
#define DIM     64
#define HID     256
#define TSTEPS  200
#define SROWS   16                 // samples per block (MFMA N)
#define NBLOCKS (BATCH / SROWS)    // 256 blocks = 1 per CU
#define NTH     512                // 8 waves, 2 per SIMD

#define HP  264   // shorts: h1s/h2s row stride ([sample][h])
#define YPB 72    // shorts: ybt row stride ([sample][d])

typedef __bf16 bf16_t;
typedef bf16_t bf16x8 __attribute__((ext_vector_type(8)));
typedef float  f32x4  __attribute__((ext_vector_type(4)));

__device__ __forceinline__ unsigned short f2bf(float f) {
    unsigned u = __builtin_bit_cast(unsigned, f);
    u += 0x7FFFu + ((u >> 16) & 1u);   // RNE
    return (unsigned short)(u >> 16);
}

#if __has_builtin(__builtin_amdgcn_cvt_pk_bf16_f32)
__device__ __forceinline__ unsigned pk2(float lo, float hi) {
    return __builtin_bit_cast(unsigned, __builtin_amdgcn_cvt_pk_bf16_f32(lo, hi));
}
#else
__device__ __forceinline__ unsigned pk2(float lo, float hi) {
    return (unsigned)f2bf(lo) | ((unsigned)f2bf(hi) << 16);
}
#endif

// NOTE (R2/R3 lesson): an lgkm-only inline-asm barrier (skipping the vmcnt
// drain) measured +170 cy/step SLOWER than plain __syncthreads(): the vmcnt
// drain overlaps the barrier wait (~free), while the opaque asm + "memory"
// clobber defeats the compiler's cross-phase scheduling. Keep __syncthreads().

// ---------------------------------------------------------------------------
// Weight prep: fp32 row-major W[K][M] -> bf16 MFMA A-fragment order of W^T.
//
// The hidden dim (H=256) uses a sigma-PERMUTED storage order so the GEMM1/2
// epilogues can write one contiguous b128 per lane:
//   stored position p = w*32 + quad*8 + mt*4 + r  <->  logical h-index
//   pi(p)            = w*32 + mt*16  + quad*4 + r
// The MFMA m-side maps through as identity (A-frag m = g*16+l16 and the C/D
// row mu = quad*4+r both land at logical g*16+mu), so only the K-side of
// W2 and W3 needs the permutation:
//   elem j of an A-frag reads logical k = kk*32 + (j>>2)*16 + quad*4 + (j&3)
// W1's K-dim is the y-dim (unpermuted): k = kk*32 + quad*8 + j.
//   W1^T: u = (mt*2+kk)*64+lane            mt:0..15, kk:0..1
//   W2^T: u = 2048 + (mt*8+kk)*64+lane     mt:0..15, kk:0..7
//   W3^T: u = 10240 + (mt*8+kk)*64+lane    mt:0..3,  kk:0..7
// ---------------------------------------------------------------------------
__global__ void prep_weights(const float* __restrict__ W1,
                             const float* __restrict__ W2,
                             const float* __restrict__ W3,
                             unsigned short* __restrict__ ws) {
    int u = blockIdx.x * blockDim.x + threadIdx.x;
    if (u >= 12288) return;
    const int lane = u & 63, l16 = lane & 15, quad = lane >> 4;
    const float* src; int ld, m, kk; bool perm;
    if (u < 2048) {
        int r = u >> 6; kk = r & 1; int mt = r >> 1;
        src = W1; ld = 256; m = mt * 16 + l16; perm = false;
    } else if (u < 10240) {
        int r = (u - 2048) >> 6; kk = r & 7; int mt = r >> 3;
        src = W2; ld = 256; m = mt * 16 + l16; perm = true;
    } else {
        int r = (u - 10240) >> 6; kk = r & 7; int mt = r >> 3;
        src = W3; ld = 64;  m = mt * 16 + l16; perm = true;
    }
    unsigned short tmp[8] __attribute__((aligned(16)));
    #pragma unroll
    for (int j = 0; j < 8; ++j) {
        int k = perm ? kk * 32 + ((j >> 2) << 4) + quad * 4 + (j & 3)
                     : kk * 32 + quad * 8 + j;
        tmp[j] = f2bf(src[(size_t)k * ld + m]);
    }
    *(uint4*)(ws + (size_t)u * 8) = *(const uint4*)tmp;
}

// ---------------------------------------------------------------------------
// Persistent ODE kernel, transposed: h^T[H x 16 samples].
// 8 waves / 2 per SIMD. A = weight^T frags (registers/AGPRs), B =
// activations^T (LDS), C/D: row = h-idx (quad*4+r), col = sample (l16).
// Biases pre-loaded into the MFMA C operand. sigma-permuted h-layout ->
// each epilogue is a single ds_write_b128 per lane.
// ---------------------------------------------------------------------------
__global__ void __launch_bounds__(NTH, 2)
ode_kernel(const float* __restrict__ y0,
           const float* __restrict__ tarr,
           const float* __restrict__ b1,
           const float* __restrict__ b2,
           const float* __restrict__ b3,
           const unsigned short* __restrict__ wf,
           float* __restrict__ out) {
    __shared__ __align__(16) unsigned short ybt[SROWS * YPB];
    __shared__ __align__(16) unsigned short h1s[SROWS * HP];
    __shared__ __align__(16) unsigned short h2s[SROWS * HP];

    const int tid  = threadIdx.x;
    const int w    = tid >> 6;        // wave 0..7
    const int lane = tid & 63;
    const int l16  = lane & 15;       // sample within tile
    const int quad = lane >> 4;
    const int b0   = blockIdx.x * SROWS;

    const float dt = tarr[1] - tarr[0];

    // --- resident weight fragments ---
    const bf16x8* wv = (const bf16x8*)wf;
    bf16x8 w1f[2][2], w2f[2][8], w3f[8];
    #pragma unroll
    for (int mt = 0; mt < 2; ++mt) {
        const int g = w * 2 + mt;
        #pragma unroll
        for (int kk = 0; kk < 2; ++kk) w1f[mt][kk] = wv[(g * 2 + kk) * 64 + lane];
        #pragma unroll
        for (int kk = 0; kk < 8; ++kk) w2f[mt][kk] = wv[2048 + (g * 8 + kk) * 64 + lane];
    }
    if (w < 4)
        #pragma unroll
        for (int kk = 0; kk < 8; ++kk) w3f[kk] = wv[10240 + (w * 8 + kk) * 64 + lane];

    // --- biases in MFMA C/D layout (logical row = base + quad*4 + r) ---
    f32x4 binit1[2], binit2[2], binit3;
    #pragma unroll
    for (int mt = 0; mt < 2; ++mt)
        #pragma unroll
        for (int r = 0; r < 4; ++r) {
            binit1[mt][r] = b1[w * 32 + mt * 16 + quad * 4 + r];
            binit2[mt][r] = b2[w * 32 + mt * 16 + quad * 4 + r];
        }

    // --- init y-state (waves 0-3) + t=0 output + ybt ---
    float yreg[4];
    float* outp = out;   // running per-thread output pointer (waves 0-3)
    if (w < 4) {
        #pragma unroll
        for (int r = 0; r < 4; ++r) binit3[r] = b3[w * 16 + quad * 4 + r];
        outp = out + (size_t)(b0 + l16) * (TSTEPS * DIM) + w * 16 + quad * 4;
        float4 v = *(const float4*)&y0[(size_t)(b0 + l16) * DIM + w * 16 + quad * 4];
        yreg[0] = v.x; yreg[1] = v.y; yreg[2] = v.z; yreg[3] = v.w;
        uint2 p; p.x = pk2(v.x, v.y); p.y = pk2(v.z, v.w);
        *(uint2*)&ybt[l16 * YPB + w * 16 + quad * 4] = p;
        *(float4*)outp = v;
        outp += DIM;
    }
    __syncthreads();

    const unsigned short* ybase  = &ybt[l16 * YPB];
    const unsigned short* h1base = &h1s[l16 * HP];
    const unsigned short* h2base = &h2s[l16 * HP];
    // sigma-layout epilogue offset: one contiguous 16B slot per lane
    const int ep_off = l16 * HP + w * 32 + quad * 8;

    for (int t = 1; t < TSTEPS; ++t) {
        // ---- GEMM1: h1^T = relu(W1^T @ y^T + b1) ----
        {
            f32x4 acc[2] = {binit1[0], binit1[1]};
            bf16x8 bfr[2];
            #pragma unroll
            for (int kk = 0; kk < 2; ++kk)
                bfr[kk] = *(const bf16x8*)&ybase[kk * 32 + quad * 8];
            #pragma unroll
            for (int kk = 0; kk < 2; ++kk)
                #pragma unroll
                for (int mt = 0; mt < 2; ++mt)
                    acc[mt] = __builtin_amdgcn_mfma_f32_16x16x32_bf16(
                        w1f[mt][kk], bfr[kk], acc[mt], 0, 0, 0);
            uint4 p;
            p.x = pk2(acc[0][0] > 0.f ? acc[0][0] : 0.f, acc[0][1] > 0.f ? acc[0][1] : 0.f);
            p.y = pk2(acc[0][2] > 0.f ? acc[0][2] : 0.f, acc[0][3] > 0.f ? acc[0][3] : 0.f);
            p.z = pk2(acc[1][0] > 0.f ? acc[1][0] : 0.f, acc[1][1] > 0.f ? acc[1][1] : 0.f);
            p.w = pk2(acc[1][2] > 0.f ? acc[1][2] : 0.f, acc[1][3] > 0.f ? acc[1][3] : 0.f);
            *(uint4*)&h1s[ep_off] = p;
        }
        __syncthreads();

        // ---- GEMM2: h2^T = relu(W2^T @ h1^T + b2) ----
        {
            f32x4 acc[2] = {binit2[0], binit2[1]};
            bf16x8 bfr[8];
            #pragma unroll
            for (int kk = 0; kk < 8; ++kk)
                bfr[kk] = *(const bf16x8*)&h1base[kk * 32 + quad * 8];
            #pragma unroll
            for (int kk = 0; kk < 8; ++kk)
                #pragma unroll
                for (int mt = 0; mt < 2; ++mt)
                    acc[mt] = __builtin_amdgcn_mfma_f32_16x16x32_bf16(
                        w2f[mt][kk], bfr[kk], acc[mt], 0, 0, 0);
            uint4 p;
            p.x = pk2(acc[0][0] > 0.f ? acc[0][0] : 0.f, acc[0][1] > 0.f ? acc[0][1] : 0.f);
            p.y = pk2(acc[0][2] > 0.f ? acc[0][2] : 0.f, acc[0][3] > 0.f ? acc[0][3] : 0.f);
            p.z = pk2(acc[1][0] > 0.f ? acc[1][0] : 0.f, acc[1][1] > 0.f ? acc[1][1] : 0.f);
            p.w = pk2(acc[1][2] > 0.f ? acc[1][2] : 0.f, acc[1][3] > 0.f ? acc[1][3] : 0.f);
            *(uint4*)&h2s[ep_off] = p;
        }
        __syncthreads();

        // ---- GEMM3 (waves 0-3): dy^T = W3^T @ h2^T + b3; y += dt*dy ----
        if (w < 4) {
            f32x4 accA = binit3;
            f32x4 accB = {0.f, 0.f, 0.f, 0.f};   // 2 chains halve dep latency
            bf16x8 bfr[8];
            #pragma unroll
            for (int kk = 0; kk < 8; ++kk)
                bfr[kk] = *(const bf16x8*)&h2base[kk * 32 + quad * 8];
            #pragma unroll
            for (int k = 0; k < 4; ++k) {
                accA = __builtin_amdgcn_mfma_f32_16x16x32_bf16(
                    w3f[k], bfr[k], accA, 0, 0, 0);
                accB = __builtin_amdgcn_mfma_f32_16x16x32_bf16(
                    w3f[k + 4], bfr[k + 4], accB, 0, 0, 0);
            }
            f32x4 acc = accA + accB;
            #pragma unroll
            for (int r = 0; r < 4; ++r)
                yreg[r] = __builtin_fmaf(dt, acc[r], yreg[r]);
            uint2 p; p.x = pk2(yreg[0], yreg[1]); p.y = pk2(yreg[2], yreg[3]);
            *(uint2*)&ybt[l16 * YPB + w * 16 + quad * 4] = p;
            float4 ov; ov.x = yreg[0]; ov.y = yreg[1]; ov.z = yreg[2]; ov.w = yreg[3];
            *(float4*)outp = ov;
            outp += DIM;
        }
        __syncthreads();
    }
}

extern "C" void kernel_launch(void* const* d_in, const int* in_sizes, int n_in,
                              void* d_out, int out_size, void* d_ws, size_t ws_size,
                              hipStream_t stream) {
    const float* y0 = (const float*)d_in[0];
    const float* t  = (const float*)d_in[1];
    const float* W1 = (const float*)d_in[2];
    const float* b1 = (const float*)d_in[3];
    const float* W2 = (const float*)d_in[4];
    const float* b2 = (const float*)d_in[5];
    const float* W3 = (const float*)d_in[6];
    const float* b3 = (const float*)d_in[7];
    float* out = (float*)d_out;
    unsigned short* wf = (unsigned short*)d_ws;   // 12288 * 16B = 192 KiB

    prep_weights<<<48, 256, 0, stream>>>(W1, W2, W3, wf);
    ode_kernel<<<NBLOCKS, NTH, 0, stream>>>(y0, t, b1, b2, b3, wf, out);
}